// Round 1
// baseline (476.550 us; speedup 1.0000x reference)
//
#include <hip/hip_runtime.h>
#include <math.h>

#define NB 16
#define NT 363
#define NC 180

__device__ __forceinline__ float gelu_f(float x) {
  return 0.5f * x * (1.0f + erff(x * 0.7071067811865475244f));
}

// ---------------- quantum gate primitives ----------------
// state index s (8 bits): lane = s[7:2], local j = s[1:0]. wire w <-> bit 7-w.

template<int P>
__device__ __forceinline__ void ryg(float* re, float* im, float c, float s, int lane) {
  if constexpr (P >= 2) {
    constexpr int mask = 1 << (P - 2);
    float sg = ((lane >> (P - 2)) & 1) ? s : -s;
#pragma unroll
    for (int j = 0; j < 4; ++j) {
      float br = __shfl_xor(re[j], mask);
      float bi = __shfl_xor(im[j], mask);
      re[j] = fmaf(c, re[j], sg * br);
      im[j] = fmaf(c, im[j], sg * bi);
    }
  } else {
#pragma unroll
    for (int k = 0; k < 2; ++k) {
      const int a = (P == 0) ? 2 * k : k;
      const int b = (P == 0) ? a + 1 : a + 2;
      float r0 = re[a], i0 = im[a], r1 = re[b], i1 = im[b];
      re[a] = fmaf(c, r0, -s * r1); im[a] = fmaf(c, i0, -s * i1);
      re[b] = fmaf(s, r0,  c * r1); im[b] = fmaf(s, i0,  c * i1);
    }
  }
}

template<int PC, int PT>
__device__ __forceinline__ void crxg(float* re, float* im, float cs, float sn, int lane) {
  if constexpr (PT >= 2) {
    constexpr int mask = 1 << (PT - 2);
#pragma unroll
    for (int j = 0; j < 4; ++j) {
      float br = __shfl_xor(re[j], mask);
      float bi = __shfl_xor(im[j], mask);
      bool ctrl;
      if constexpr (PC >= 2) ctrl = ((lane >> (PC - 2)) & 1) != 0;
      else                   ctrl = ((j >> PC) & 1) != 0;
      if (ctrl) {
        float nr = fmaf(cs, re[j],  sn * bi);
        float ni = fmaf(cs, im[j], -sn * br);
        re[j] = nr; im[j] = ni;
      }
    }
  } else {
#pragma unroll
    for (int k = 0; k < 2; ++k) {
      const int a = (PT == 0) ? 2 * k : k;
      const int b = (PT == 0) ? a + 1 : a + 2;
      bool ctrl;
      if constexpr (PC >= 2) ctrl = ((lane >> (PC - 2)) & 1) != 0;
      else                   ctrl = ((a >> PC) & 1) != 0;
      if (ctrl) {
        float r0 = re[a], i0 = im[a], r1 = re[b], i1 = im[b];
        re[a] = fmaf(cs, r0,  sn * i1); im[a] = fmaf(cs, i0, -sn * r1);
        re[b] = fmaf(cs, r1,  sn * i0); im[b] = fmaf(cs, i1, -sn * r0);
      }
    }
  }
}

__device__ __forceinline__ void sim14_layer(float* re, float* im,
                                            const float* Cr, const float* Sr, int lane) {
#define ARY(q, pi) ryg<7-(q)>(re, im, Cr[pi], Sr[pi], lane)
#define ACX(cq, tq, pi) crxg<7-(cq), 7-(tq)>(re, im, Cr[pi], Sr[pi], lane)
  ARY(0,0); ARY(1,1); ARY(2,2); ARY(3,3); ARY(4,4); ARY(5,5); ARY(6,6); ARY(7,7);
  ACX(0,1,8); ACX(1,2,9); ACX(2,3,10); ACX(3,4,11); ACX(4,5,12); ACX(5,6,13); ACX(6,7,14); ACX(7,0,15);
  ARY(0,16); ARY(1,17); ARY(2,18); ARY(3,19); ARY(4,20); ARY(5,21); ARY(6,22); ARY(7,23);
  ACX(0,7,24); ACX(1,0,25); ACX(2,1,26); ACX(3,2,27); ACX(4,3,28); ACX(5,4,29); ACX(6,5,30); ACX(7,6,31);
#undef ARY
#undef ACX
}

// ---------------- K1: embed (B,T,180) -> ht (B,96,T) with GELU ----------------
__global__ __launch_bounds__(256) void k_embed(const float* __restrict__ x,
                                               const float* __restrict__ nw,
                                               const float* __restrict__ nb,
                                               float* __restrict__ ht) {
  int b = blockIdx.x, tile = blockIdx.y, tid = threadIdx.x;
  int t0 = tile * 32;
  __shared__ float xt[32][181];
  __shared__ float nwL[1440];
  __shared__ float nbL[96];
  for (int i = tid; i < 1440; i += 256) nwL[i] = nw[i];
  for (int i = tid; i < 96; i += 256) nbL[i] = nb[i];
  for (int i = tid; i < 32 * 180; i += 256) {
    int tt = i / 180, c = i % 180;
    int t = t0 + tt;
    xt[tt][c] = (t < NT) ? x[(b * NT + t) * NC + c] : 0.0f;
  }
  __syncthreads();
  int tt = tid & 31, cs = tid >> 5; // cs in [0,8)
  int t = t0 + tt;
  if (t < NT) {
    for (int pass = 0; pass < 12; ++pass) {
      int k = pass, d = cs;
      int c = k * 8 + d;
      float acc = nbL[k * 8 + d];
#pragma unroll
      for (int i = 0; i < 15; ++i)
        acc = fmaf(xt[tt][k * 15 + i], nwL[(k * 15 + i) * 8 + d], acc);
      ht[(b * 96 + c) * NT + t] = gelu_f(acc);
    }
  }
}

// ---------------- K2: depthwise conv, all 3 branches ----------------
__global__ __launch_bounds__(384) void k_dw(const float* __restrict__ ht,
    const float* __restrict__ wa, const float* __restrict__ ba,
    const float* __restrict__ wb, const float* __restrict__ bb,
    const float* __restrict__ wc, const float* __restrict__ bc,
    float* __restrict__ y1a, float* __restrict__ y1b, float* __restrict__ y1c) {
  int bc_idx = blockIdx.x; // b*96 + c
  int c = bc_idx % 96;
  int tid = threadIdx.x;
  __shared__ float rowL[NT];
  if (tid < NT) rowL[tid] = ht[bc_idx * NT + tid];
  __syncthreads();
  if (tid < NT) {
    {
      float acc = ba[c];
#pragma unroll
      for (int k = 0; k < 7; ++k) {
        int idx = tid + (k - 3);
        if (idx >= 0 && idx < NT) acc = fmaf(rowL[idx], wa[c * 7 + k], acc);
      }
      y1a[bc_idx * NT + tid] = acc;
    }
    {
      float acc = bb[c];
#pragma unroll
      for (int k = 0; k < 7; ++k) {
        int idx = tid + (k - 3) * 4;
        if (idx >= 0 && idx < NT) acc = fmaf(rowL[idx], wb[c * 7 + k], acc);
      }
      y1b[bc_idx * NT + tid] = acc;
    }
    {
      float acc = bc[c];
#pragma unroll
      for (int k = 0; k < 7; ++k) {
        int idx = tid + (k - 3) * 16;
        if (idx >= 0 && idx < NT) acc = fmaf(rowL[idx], wc[c * 7 + k], acc);
      }
      y1c[bc_idx * NT + tid] = acc;
    }
  }
}

// ---------------- K3: pointwise 96x96 ----------------
__global__ __launch_bounds__(256) void k_pw(const float* __restrict__ y1,
                                            const float* __restrict__ pw_w,
                                            const float* __restrict__ pw_b,
                                            float* __restrict__ y2) {
  int b = blockIdx.x, tile = blockIdx.y, tid = threadIdx.x;
  int t0 = tile * 64;
  __shared__ float y1t[96 * 64];
  __shared__ float pwL[96 * 97]; // pad 97 to break 96-stride bank aliasing
  for (int i = tid; i < 96 * 96; i += 256) {
    int o = i / 96, cc = i % 96;
    pwL[o * 97 + cc] = pw_w[i];
  }
  for (int i = tid; i < 96 * 64; i += 256) {
    int cc = i >> 6, t = i & 63;
    int tt = t0 + t;
    y1t[i] = (tt < NT) ? y1[(b * 96 + cc) * NT + tt] : 0.0f;
  }
  __syncthreads();
  int o16 = tid >> 4, t4 = (tid & 15) * 4;
  for (int pass = 0; pass < 6; ++pass) {
    int o = pass * 16 + o16;
    float bias = pw_b[o];
    float a0 = bias, a1 = bias, a2 = bias, a3 = bias;
    const float* wrow = &pwL[o * 97];
#pragma unroll 4
    for (int cc = 0; cc < 96; ++cc) {
      const float4 vy = *reinterpret_cast<const float4*>(&y1t[cc * 64 + t4]);
      float w = wrow[cc];
      a0 = fmaf(w, vy.x, a0); a1 = fmaf(w, vy.y, a1);
      a2 = fmaf(w, vy.z, a2); a3 = fmaf(w, vy.w, a3);
    }
    int base = (b * 96 + o) * NT;
    int t = t0 + t4;
    if (t + 3 < NT) {
      y2[base + t] = a0; y2[base + t + 1] = a1; y2[base + t + 2] = a2; y2[base + t + 3] = a3;
    } else {
      if (t < NT) y2[base + t] = a0;
      if (t + 1 < NT) y2[base + t + 1] = a1;
      if (t + 2 < NT) y2[base + t + 2] = a2;
      if (t + 3 < NT) y2[base + t + 3] = a3;
    }
  }
}

// ---------------- K4: groupnorm stats (two-pass) ----------------
__global__ __launch_bounds__(256) void k_gnstat(const float* __restrict__ y2,
                                                float* __restrict__ muG,
                                                float* __restrict__ rsG) {
  int b = blockIdx.x, g = blockIdx.y, tid = threadIdx.x;
  __shared__ float red[256];
  const float* base = y2 + (b * 96 + g * 12) * NT;
  float s = 0;
  for (int i = tid; i < 12 * NT; i += 256) s += base[i];
  red[tid] = s; __syncthreads();
  for (int st = 128; st > 0; st >>= 1) { if (tid < st) red[tid] += red[tid + st]; __syncthreads(); }
  float mu = red[0] / 4356.0f;
  __syncthreads();
  float q = 0;
  for (int i = tid; i < 12 * NT; i += 256) { float d = base[i] - mu; q = fmaf(d, d, q); }
  red[tid] = q; __syncthreads();
  for (int st = 128; st > 0; st >>= 1) { if (tid < st) red[tid] += red[tid + st]; __syncthreads(); }
  if (tid == 0) {
    float var = red[0] / 4356.0f;
    muG[b * 8 + g] = mu;
    rsG[b * 8 + g] = rsqrtf(var + 1e-5f);
  }
}

// ---------------- K5: groupnorm apply + gelu -> cat (B*T,288) ----------------
__global__ __launch_bounds__(256) void k_gnapply(const float* __restrict__ y2,
    const float* __restrict__ muG, const float* __restrict__ rsG,
    const float* __restrict__ gng, const float* __restrict__ gnb,
    float* __restrict__ cat, int br) {
  int b = blockIdx.x, tile = blockIdx.y, tid = threadIdx.x;
  int t0 = tile * 64;
  __shared__ float yL[96 * 65];
  __shared__ float muL[8], rsL[8];
  if (tid < 8) { muL[tid] = muG[b * 8 + tid]; rsL[tid] = rsG[b * 8 + tid]; }
  for (int i = tid; i < 96 * 64; i += 256) {
    int cc = i >> 6, t = i & 63;
    int tt = t0 + t;
    yL[cc * 65 + t] = (tt < NT) ? y2[(b * 96 + cc) * NT + tt] : 0.0f;
  }
  __syncthreads();
  for (int i = tid; i < 64 * 96; i += 256) {
    int tt = i / 96, cc = i % 96;
    int t = t0 + tt;
    if (t < NT) {
      int g = cc / 12;
      float v = (yL[cc * 65 + tt] - muL[g]) * rsL[g] * gng[cc] + gnb[cc];
      cat[(b * NT + t) * 288 + br * 96 + cc] = gelu_f(v);
    }
  }
}

// ---------------- K6: merge GEMM + LN + GELU + qproj + sigmoid -> cos/sin ----------------
__global__ __launch_bounds__(256) void k_merge(const float* __restrict__ cat,
    const float* __restrict__ mw, const float* __restrict__ mb,
    const float* __restrict__ lng, const float* __restrict__ lnb,
    const float* __restrict__ qw, const float* __restrict__ qb,
    float* __restrict__ csG, float* __restrict__ snG) {
  int blk = blockIdx.x, tid = threadIdx.x;
  __shared__ float catL[8][288];
  __shared__ float vL[8][129];
  __shared__ float hL[8][129];
  __shared__ float muS[8], rsS[8];
  for (int i = tid; i < 8 * 288; i += 256) {
    int r = i / 288, k = i % 288;
    catL[r][k] = cat[(blk * 8 + r) * 288 + k];
  }
  __syncthreads();
  int jj = tid & 127, rg = tid >> 7;
  float bias = mb[jj];
  float acc[4] = {bias, bias, bias, bias};
  for (int k = 0; k < 288; ++k) {
    float w = mw[k * 128 + jj];
#pragma unroll
    for (int r = 0; r < 4; ++r) acc[r] = fmaf(catL[rg * 4 + r][k], w, acc[r]);
  }
#pragma unroll
  for (int r = 0; r < 4; ++r) vL[rg * 4 + r][jj] = acc[r];
  __syncthreads();
  if (tid < 8) {
    float s = 0;
    for (int k = 0; k < 128; ++k) s += vL[tid][k];
    float mu = s / 128.0f;
    float q = 0;
    for (int k = 0; k < 128; ++k) { float d = vL[tid][k] - mu; q = fmaf(d, d, q); }
    muS[tid] = mu;
    rsS[tid] = rsqrtf(q / 128.0f + 1e-5f);
  }
  __syncthreads();
  float g = lng[jj], bb2 = lnb[jj];
#pragma unroll
  for (int r = 0; r < 4; ++r) {
    int row = rg * 4 + r;
    float h = (acc[r] - muS[row]) * rsS[row] * g + bb2;
    hL[row][jj] = gelu_f(h);
  }
  __syncthreads();
  int o = tid & 63;
  int r0 = (tid >> 6) * 2;
  for (int rr = 0; rr < 2; ++rr) {
    int row = r0 + rr;
    float u = qb[o];
    for (int k = 0; k < 128; ++k) u = fmaf(hL[row][k], qw[k * 64 + o], u);
    float tp = 6.2831853071795864769f / (1.0f + expf(-u));
    float hf = tp * 0.5f;
    int grow = blk * 8 + row;
    csG[grow * 64 + o] = cosf(hf);
    snG[grow * 64 + o] = sinf(hf);
  }
}

// ---------------- K7: quantum ansatz, 1 wave per (b,t) row ----------------
__global__ __launch_bounds__(256) void k_quantum(const float* __restrict__ csG,
                                                 const float* __restrict__ snG,
                                                 const float* __restrict__ pc4,
                                                 float* __restrict__ accG /* float2 as float */) {
  __shared__ float csL[4][64], snL[4][64];
  int wave = threadIdx.x >> 6, lane = threadIdx.x & 63;
  int row = blockIdx.x * 4 + wave;
  csL[wave][lane] = csG[row * 64 + lane];
  snL[wave][lane] = snG[row * 64 + lane];
  __syncthreads();
  float p0 = pc4[0], p1 = pc4[1], p2 = pc4[2], p3 = pc4[3];
  float re[4] = {0, 0, 0, 0}, im[4] = {0, 0, 0, 0};
  if (lane == 0) re[0] = 1.0f;
  float ar[4], ai[4];
#pragma unroll
  for (int j = 0; j < 4; ++j) { ar[j] = p0 * re[j]; ai[j] = 0.0f; }
  const float* Call = &csL[wave][0];
  const float* Sall = &snL[wave][0];
  for (int rep = 0; rep < 3; ++rep) {
    for (int layer = 0; layer < 2; ++layer) {
      sim14_layer(re, im, Call + layer * 32, Sall + layer * 32, lane);
    }
    float pc = (rep == 0) ? p1 : (rep == 1) ? p2 : p3;
#pragma unroll
    for (int j = 0; j < 4; ++j) { ar[j] = fmaf(pc, re[j], ar[j]); ai[j] = fmaf(pc, im[j], ai[j]); }
  }
  float4* p4 = reinterpret_cast<float4*>(accG + (size_t)(row * 256 + lane * 4) * 2);
  p4[0] = make_float4(ar[0], ai[0], ar[1], ai[1]);
  p4[1] = make_float4(ar[2], ai[2], ar[3], ai[3]);
}

// ---------------- K8: mix over T + normalize -> psi ----------------
__global__ __launch_bounds__(256) void k_mix(const float* __restrict__ accG,
                                             const float* __restrict__ mr,
                                             const float* __restrict__ mi,
                                             float* __restrict__ psiG) {
  int b = blockIdx.x, d = threadIdx.x;
  float sr = 0, si = 0;
  for (int t = 0; t < NT; ++t) {
    const float2 a = *reinterpret_cast<const float2*>(accG + (size_t)((b * NT + t) * 256 + d) * 2);
    float m_r = mr[t], m_i = mi[t];
    sr = fmaf(m_r, a.x, fmaf(-m_i, a.y, sr));
    si = fmaf(m_r, a.y, fmaf(m_i, a.x, si));
  }
  __shared__ float red[256];
  red[d] = sr * sr + si * si;
  __syncthreads();
  for (int s = 128; s > 0; s >>= 1) { if (d < s) red[d] += red[d + s]; __syncthreads(); }
  float nrm = sqrtf(red[0]) + 1e-9f;
  float2* out = reinterpret_cast<float2*>(psiG + (size_t)(b * 256 + d) * 2);
  *out = make_float2(sr / nrm, si / nrm);
}

// ---------------- K9: final ansatz layer + pauli expvals + qout -> fused[0:128] ----------------
__global__ __launch_bounds__(64) void k_qff(const float* __restrict__ psiG,
                                            const float* __restrict__ qff,
                                            const float* __restrict__ qout_w,
                                            const float* __restrict__ qout_b,
                                            float* __restrict__ fused) {
  int b = blockIdx.x, lane = threadIdx.x;
  float re[4], im[4];
#pragma unroll
  for (int j = 0; j < 4; ++j) {
    const float2 v = *reinterpret_cast<const float2*>(psiG + (size_t)(b * 256 + lane * 4 + j) * 2);
    re[j] = v.x; im[j] = v.y;
  }
  __shared__ float qcL[32], qsL[32];
  if (lane < 32) { float h = qff[lane] * 0.5f; qcL[lane] = cosf(h); qsL[lane] = sinf(h); }
  __syncthreads();
  sim14_layer(re, im, qcL, qsL, lane);
  __shared__ float sre[256], sIm[256], exps[24];
#pragma unroll
  for (int j = 0; j < 4; ++j) { sre[lane * 4 + j] = re[j]; sIm[lane * 4 + j] = im[j]; }
  __syncthreads();
  for (int w = 0; w < 8; ++w) {
    int p = 7 - w;
    float cr = 0, ci = 0, z = 0;
#pragma unroll
    for (int k = 0; k < 2; ++k) {
      int pr = lane + k * 64;
      int lowmask = (1 << p) - 1;
      int i0 = ((pr >> p) << (p + 1)) | (pr & lowmask);
      int i1 = i0 | (1 << p);
      float r0 = sre[i0], I0 = sIm[i0], r1 = sre[i1], I1 = sIm[i1];
      cr += r0 * r1 + I0 * I1;
      ci += r0 * I1 - I0 * r1;
      z += r0 * r0 + I0 * I0 - r1 * r1 - I1 * I1;
    }
    for (int off = 32; off > 0; off >>= 1) {
      cr += __shfl_down(cr, off);
      ci += __shfl_down(ci, off);
      z  += __shfl_down(z, off);
    }
    if (lane == 0) { exps[w] = 2.0f * cr; exps[8 + w] = 2.0f * ci; exps[16 + w] = z; }
  }
  __syncthreads();
  for (int rpt = 0; rpt < 2; ++rpt) {
    int j = lane + rpt * 64;
    float v = qout_b[j];
#pragma unroll
    for (int k = 0; k < 24; ++k) v = fmaf(exps[k], qout_w[k * 128 + j], v);
    fused[b * 192 + j] = v;
  }
}

// ---------------- K10: correlation path -> fused[128:192] ----------------
__global__ __launch_bounds__(256) void k_corr(const float* __restrict__ x,
                                              const float* __restrict__ fcw,
                                              const float* __restrict__ fcb,
                                              float* __restrict__ fused) {
  int b = blockIdx.x, tid = threadIdx.x;
  __shared__ float muL[180], invL[180];
  __shared__ float SL[NT * 12];
  __shared__ float fcv[78];
  if (tid < 180) {
    float s = 0;
    const float* px = x + (size_t)b * NT * NC + tid;
    for (int t = 0; t < NT; ++t) s += px[t * NC];
    float mu = s / 363.0f;
    float q = 0;
    for (int t = 0; t < NT; ++t) { float d = px[t * NC] - mu; q = fmaf(d, d, q); }
    float sd = sqrtf(q / 362.0f);
    sd = fmaxf(sd, 1e-8f);
    muL[tid] = mu; invL[tid] = 1.0f / sd;
  }
  __syncthreads();
  for (int t = tid; t < NT; t += 256) {
    const float* px = x + (size_t)(b * NT + t) * NC;
#pragma unroll
    for (int i = 0; i < 12; ++i) {
      float s = 0;
#pragma unroll
      for (int u = 0; u < 15; ++u) {
        int cidx = i * 15 + u;
        s += (px[cidx] - muL[cidx]) * invL[cidx];
      }
      SL[t * 12 + i] = s;
    }
  }
  __syncthreads();
  if (tid < 78) {
    int i = 0, rem = tid;
    while (rem >= 12 - i) { rem -= 12 - i; ++i; }
    int j = i + rem;
    float acc = 0;
    for (int t = 0; t < NT; ++t) acc = fmaf(SL[t * 12 + i], SL[t * 12 + j], acc);
    fcv[tid] = acc * (1.0f / (225.0f * 362.0f));
  }
  __syncthreads();
  if (tid < 64) {
    float v = fcb[tid];
#pragma unroll
    for (int k = 0; k < 78; ++k) v = fmaf(fcv[k], fcw[k * 64 + tid], v);
    fused[b * 192 + 128 + tid] = gelu_f(v);
  }
}

// ---------------- K11: final MLP ----------------
__global__ __launch_bounds__(128) void k_final(const float* __restrict__ fused,
    const float* __restrict__ w1, const float* __restrict__ b1,
    const float* __restrict__ lng, const float* __restrict__ lnb,
    const float* __restrict__ w2, const float* __restrict__ b2,
    float* __restrict__ out) {
  int b = blockIdx.x, tid = threadIdx.x;
  __shared__ float fL[192], red[128], hL[128];
  for (int i = tid; i < 192; i += 128) fL[i] = fused[b * 192 + i];
  __syncthreads();
  float v = b1[tid];
  for (int k = 0; k < 192; ++k) v = fmaf(fL[k], w1[k * 128 + tid], v);
  red[tid] = v; __syncthreads();
  for (int s = 64; s > 0; s >>= 1) { if (tid < s) red[tid] += red[tid + s]; __syncthreads(); }
  float mu = red[0] / 128.0f; __syncthreads();
  float dv = v - mu;
  red[tid] = dv * dv; __syncthreads();
  for (int s = 64; s > 0; s >>= 1) { if (tid < s) red[tid] += red[tid + s]; __syncthreads(); }
  float var = red[0] / 128.0f;
  float h = gelu_f(dv * rsqrtf(var + 1e-5f) * lng[tid] + lnb[tid]);
  hL[tid] = h; __syncthreads();
  if (tid < 64) {
    float o = b2[tid];
    for (int k = 0; k < 128; ++k) o = fmaf(hL[k], w2[k * 64 + tid], o);
    out[b * 64 + tid] = o;
  }
}

extern "C" void kernel_launch(void* const* d_in, const int* in_sizes, int n_in,
                              void* d_out, int out_size, void* d_ws, size_t ws_size,
                              hipStream_t stream) {
  const float* x       = (const float*)d_in[0];
  const float* net_w   = (const float*)d_in[1];
  const float* net_b   = (const float*)d_in[2];
  const float* dwa_w   = (const float*)d_in[3];
  const float* dwa_b   = (const float*)d_in[4];
  const float* pwa_w   = (const float*)d_in[5];
  const float* pwa_b   = (const float*)d_in[6];
  const float* gna_g   = (const float*)d_in[7];
  const float* gna_b   = (const float*)d_in[8];
  const float* dwb_w   = (const float*)d_in[9];
  const float* dwb_b   = (const float*)d_in[10];
  const float* pwb_w   = (const float*)d_in[11];
  const float* pwb_b   = (const float*)d_in[12];
  const float* gnb_g   = (const float*)d_in[13];
  const float* gnb_b   = (const float*)d_in[14];
  const float* dwc_w   = (const float*)d_in[15];
  const float* dwc_b   = (const float*)d_in[16];
  const float* pwc_w   = (const float*)d_in[17];
  const float* pwc_b   = (const float*)d_in[18];
  const float* gnc_g   = (const float*)d_in[19];
  const float* gnc_b   = (const float*)d_in[20];
  const float* merge_w = (const float*)d_in[21];
  const float* merge_b = (const float*)d_in[22];
  const float* mlng    = (const float*)d_in[23];
  const float* mlnb    = (const float*)d_in[24];
  const float* qproj_w = (const float*)d_in[25];
  const float* qproj_b = (const float*)d_in[26];
  const float* poly    = (const float*)d_in[27];
  const float* qff     = (const float*)d_in[28];
  const float* mix_re  = (const float*)d_in[29];
  const float* mix_im  = (const float*)d_in[30];
  const float* qout_w  = (const float*)d_in[31];
  const float* qout_b  = (const float*)d_in[32];
  const float* fc_w    = (const float*)d_in[33];
  const float* fc_b    = (const float*)d_in[34];
  const float* fus1_w  = (const float*)d_in[35];
  const float* fus1_b  = (const float*)d_in[36];
  const float* flng    = (const float*)d_in[37];
  const float* flnb    = (const float*)d_in[38];
  const float* fus2_w  = (const float*)d_in[39];
  const float* fus2_b  = (const float*)d_in[40];
  float* out = (float*)d_out;

  // workspace layout (floats). acc (2,973,696 floats) aliases [0 .. ) over
  // ht/y1a/y1b/y1c/y2 and the head of cat — all dead before k_quantum runs.
  float* W = (float*)d_ws;
  const size_t SZ = (size_t)NB * 96 * NT;        // 557568
  float* ht   = W + 0;
  float* y1a  = W + SZ;
  float* y1b  = W + 2 * SZ;
  float* y1c  = W + 3 * SZ;
  float* y2   = W + 4 * SZ;
  float* cat  = W + 5 * SZ;                      // 2787840, len 1672704
  float* csG  = cat + (size_t)NB * NT * 288;     // 4460544, len 371712
  float* snG  = csG + (size_t)NB * NT * 64;      // len 371712
  float* muG  = snG + (size_t)NB * NT * 64;      // len 128
  float* rsG  = muG + 128;                       // len 128
  float* psi  = rsG + 128;                       // len 8192 (16*256*2)
  float* fused = psi + 16 * 256 * 2;             // len 3072
  float* acc  = W + 0;                           // len 5808*256*2 = 2973696 (aliased)

  k_embed<<<dim3(NB, 12), 256, 0, stream>>>(x, net_w, net_b, ht);
  k_dw<<<NB * 96, 384, 0, stream>>>(ht, dwa_w, dwa_b, dwb_w, dwb_b, dwc_w, dwc_b, y1a, y1b, y1c);

  const float* pwwp[3] = {pwa_w, pwb_w, pwc_w};
  const float* pwbp[3] = {pwa_b, pwb_b, pwc_b};
  const float* gngp[3] = {gna_g, gnb_g, gnc_g};
  const float* gnbp[3] = {gna_b, gnb_b, gnc_b};
  float* y1p[3] = {y1a, y1b, y1c};
  for (int br = 0; br < 3; ++br) {
    k_pw<<<dim3(NB, 6), 256, 0, stream>>>(y1p[br], pwwp[br], pwbp[br], y2);
    k_gnstat<<<dim3(NB, 8), 256, 0, stream>>>(y2, muG, rsG);
    k_gnapply<<<dim3(NB, 6), 256, 0, stream>>>(y2, muG, rsG, gngp[br], gnbp[br], cat, br);
  }

  k_merge<<<(NB * NT) / 8, 256, 0, stream>>>(cat, merge_w, merge_b, mlng, mlnb,
                                             qproj_w, qproj_b, csG, snG);
  k_quantum<<<(NB * NT) / 4, 256, 0, stream>>>(csG, snG, poly, acc);
  k_mix<<<NB, 256, 0, stream>>>(acc, mix_re, mix_im, psi);
  k_qff<<<NB, 64, 0, stream>>>(psi, qff, qout_w, qout_b, fused);
  k_corr<<<NB, 256, 0, stream>>>(x, fc_w, fc_b, fused);
  k_final<<<NB, 128, 0, stream>>>(fused, fus1_w, fus1_b, flng, flnb, fus2_w, fus2_b, out);
}